// Round 1
// baseline (12644.221 us; speedup 1.0000x reference)
//
#include <hip/hip_runtime.h>
#include <hip/hip_bf16.h>

// Problem geometry (fixed by the reference):
//   B=8, C=128, H=W=128, SR=4 -> 81 corr channels
//   flow estimator convs: (128+81)->128->128->96->64->32, k=3 dil=1, LeakyReLU(0.1)
//   conv1 (flow head): 32->2, no activation
//   context: 34->128(d1)->128(d2)->128(d4)->96(d8)->64(d16)->32(d1)->2(d1), all LeakyReLU
//   out = flo_coarse + y

#define H_ 128
#define W_ 128
#define HW_ (H_ * W_)
#define B_ 8

// ---------------------------------------------------------------------------
// Correlation: corr[b, dy*9+dx, y, x] = (1/128) * sum_c x1[b,c,y,x] * x2[b,c,y+dy-4,x+dx-4]
// One thread per output pixel; 9 accumulators (one dy row at a time).
// Block 256 = (x:128, y:2). Grid (H/2, 1, B).
// ---------------------------------------------------------------------------
__global__ void corr_kernel(const float* __restrict__ x1,
                            const float* __restrict__ x2,
                            float* __restrict__ corr) {
    const int x = threadIdx.x & 127;
    const int y = (blockIdx.x << 1) + (threadIdx.x >> 7);
    const int b = blockIdx.z;

    const float* p1 = x1 + (size_t)b * 128 * HW_ + y * W_ + x;
    const float* p2 = x2 + (size_t)b * 128 * HW_;

    for (int dy = 0; dy < 9; ++dy) {
        const int yy = y + dy - 4;
        float acc[9];
#pragma unroll
        for (int i = 0; i < 9; ++i) acc[i] = 0.f;

        if ((unsigned)yy < (unsigned)H_) {
            for (int c = 0; c < 128; ++c) {
                const float v1 = p1[c * HW_];
                const float* row = p2 + c * HW_ + yy * W_;
#pragma unroll
                for (int dx = 0; dx < 9; ++dx) {
                    const int xx = x + dx - 4;
                    const float v2 = ((unsigned)xx < (unsigned)W_) ? row[xx] : 0.f;
                    acc[dx] = fmaf(v1, v2, acc[dx]);
                }
            }
        }
#pragma unroll
        for (int dx = 0; dx < 9; ++dx) {
            const int o = dy * 9 + dx;
            corr[((size_t)(b * 81 + o)) * HW_ + y * W_ + x] = acc[dx] * (1.f / 128.f);
        }
    }
}

// ---------------------------------------------------------------------------
// Direct 3x3 conv, NCHW, 'same' padding with dilation, optional concat of a
// second input along channels, fused LeakyReLU(0.1) and optional residual add.
// COPB output channels per thread (input load amortized over COPB FMAs;
// weights are block-uniform -> scalar loads).
// Block 256 = (x:128, y:2). Grid (H/2, Co/COPB, B).
// ---------------------------------------------------------------------------
template <int COPB>
__global__ void conv3x3(const float* __restrict__ in1, int C1,
                        const float* __restrict__ in2, int C2,
                        const float* __restrict__ w,
                        const float* __restrict__ bias,
                        float* __restrict__ out, int Co,
                        const float* __restrict__ addp,
                        int dil, int leaky) {
    const int x   = threadIdx.x & 127;
    const int y   = (blockIdx.x << 1) + (threadIdx.x >> 7);
    const int cob = blockIdx.y * COPB;
    const int b   = blockIdx.z;
    const int Ctot = C1 + C2;

    float acc[COPB];
#pragma unroll
    for (int i = 0; i < COPB; ++i) acc[i] = bias[cob + i];

    // source 1
    {
        const float* src = in1 + (size_t)b * C1 * HW_;
        const float* wc0 = w + (size_t)cob * Ctot * 9;  // + ci*9 + k
        for (int ci = 0; ci < C1; ++ci) {
            const float* ib = src + ci * HW_;
            const float* wb = wc0 + ci * 9;
#pragma unroll
            for (int ky = 0; ky < 3; ++ky) {
                const int yy = y + (ky - 1) * dil;
                if ((unsigned)yy < (unsigned)H_) {
                    const float* row = ib + yy * W_;
#pragma unroll
                    for (int kx = 0; kx < 3; ++kx) {
                        const int xx = x + (kx - 1) * dil;
                        const float v = ((unsigned)xx < (unsigned)W_) ? row[xx] : 0.f;
                        const int k = ky * 3 + kx;
#pragma unroll
                        for (int i = 0; i < COPB; ++i)
                            acc[i] = fmaf(v, wb[(size_t)i * Ctot * 9 + k], acc[i]);
                    }
                }
            }
        }
    }
    // source 2 (concat along channels)
    if (in2 != nullptr) {
        const float* src = in2 + (size_t)b * C2 * HW_;
        const float* wc0 = w + (size_t)cob * Ctot * 9 + (size_t)C1 * 9;
        for (int ci = 0; ci < C2; ++ci) {
            const float* ib = src + ci * HW_;
            const float* wb = wc0 + ci * 9;
#pragma unroll
            for (int ky = 0; ky < 3; ++ky) {
                const int yy = y + (ky - 1) * dil;
                if ((unsigned)yy < (unsigned)H_) {
                    const float* row = ib + yy * W_;
#pragma unroll
                    for (int kx = 0; kx < 3; ++kx) {
                        const int xx = x + (kx - 1) * dil;
                        const float v = ((unsigned)xx < (unsigned)W_) ? row[xx] : 0.f;
                        const int k = ky * 3 + kx;
#pragma unroll
                        for (int i = 0; i < COPB; ++i)
                            acc[i] = fmaf(v, wb[(size_t)i * Ctot * 9 + k], acc[i]);
                    }
                }
            }
        }
    }

#pragma unroll
    for (int i = 0; i < COPB; ++i) {
        float v = acc[i];
        if (leaky) v = (v >= 0.f) ? v : 0.1f * v;
        const size_t oidx = ((size_t)(b * Co + cob + i)) * HW_ + y * W_ + x;
        if (addp != nullptr) v += addp[oidx];
        out[oidx] = v;
    }
}

extern "C" void kernel_launch(void* const* d_in, const int* in_sizes, int n_in,
                              void* d_out, int out_size, void* d_ws, size_t ws_size,
                              hipStream_t stream) {
    const float* x1 = (const float*)d_in[0];
    const float* x2 = (const float*)d_in[1];
    const float* w0 = (const float*)d_in[2];
    const float* b0 = (const float*)d_in[3];
    const float* w1 = (const float*)d_in[4];
    const float* b1 = (const float*)d_in[5];
    const float* w2 = (const float*)d_in[6];
    const float* b2 = (const float*)d_in[7];
    const float* w3 = (const float*)d_in[8];
    const float* b3 = (const float*)d_in[9];
    const float* w4 = (const float*)d_in[10];
    const float* b4 = (const float*)d_in[11];
    const float* wc = (const float*)d_in[12];
    const float* bc = (const float*)d_in[13];
    const float* cw0 = (const float*)d_in[14];
    const float* cb0 = (const float*)d_in[15];
    const float* cw1 = (const float*)d_in[16];
    const float* cb1 = (const float*)d_in[17];
    const float* cw2 = (const float*)d_in[18];
    const float* cb2 = (const float*)d_in[19];
    const float* cw3 = (const float*)d_in[20];
    const float* cb3 = (const float*)d_in[21];
    const float* cw4 = (const float*)d_in[22];
    const float* cb4 = (const float*)d_in[23];
    const float* cw5 = (const float*)d_in[24];
    const float* cb5 = (const float*)d_in[25];
    const float* cw6 = (const float*)d_in[26];
    const float* cb6 = (const float*)d_in[27];

    // workspace layout (floats):
    //   corr: 8*81*16384   = 10,616,832
    //   A   : 8*128*16384  = 16,777,216
    //   B   : 8*128*16384  = 16,777,216
    // total 176,685,056 bytes
    float* corr = (float*)d_ws;
    float* A    = corr + (size_t)B_ * 81 * HW_;
    float* Bf   = A + (size_t)B_ * 128 * HW_;
    float* outp = (float*)d_out;

    const dim3 blk(256, 1, 1);

    // correlation
    corr_kernel<<<dim3(H_ / 2, 1, B_), blk, 0, stream>>>(x1, x2, corr);

    // flow estimator
    conv3x3<4><<<dim3(H_ / 2, 128 / 4, B_), blk, 0, stream>>>(x1, 128, corr, 81, w0, b0, A, 128, nullptr, 1, 1);
    conv3x3<4><<<dim3(H_ / 2, 128 / 4, B_), blk, 0, stream>>>(A, 128, nullptr, 0, w1, b1, Bf, 128, nullptr, 1, 1);
    conv3x3<4><<<dim3(H_ / 2, 96 / 4, B_),  blk, 0, stream>>>(Bf, 128, nullptr, 0, w2, b2, A, 96, nullptr, 1, 1);
    conv3x3<4><<<dim3(H_ / 2, 64 / 4, B_),  blk, 0, stream>>>(A, 96, nullptr, 0, w3, b3, Bf, 64, nullptr, 1, 1);
    conv3x3<4><<<dim3(H_ / 2, 32 / 4, B_),  blk, 0, stream>>>(Bf, 64, nullptr, 0, w4, b4, A, 32, nullptr, 1, 1);

    // flow head (no activation) -> d_out
    conv3x3<2><<<dim3(H_ / 2, 1, B_), blk, 0, stream>>>(A, 32, nullptr, 0, wc, bc, outp, 2, nullptr, 1, 0);

    // context network (input = concat(A[32], flo[2]))
    conv3x3<4><<<dim3(H_ / 2, 128 / 4, B_), blk, 0, stream>>>(A, 32, outp, 2, cw0, cb0, Bf, 128, nullptr, 1, 1);
    conv3x3<4><<<dim3(H_ / 2, 128 / 4, B_), blk, 0, stream>>>(Bf, 128, nullptr, 0, cw1, cb1, A, 128, nullptr, 2, 1);
    conv3x3<4><<<dim3(H_ / 2, 128 / 4, B_), blk, 0, stream>>>(A, 128, nullptr, 0, cw2, cb2, Bf, 128, nullptr, 4, 1);
    conv3x3<4><<<dim3(H_ / 2, 96 / 4, B_),  blk, 0, stream>>>(Bf, 128, nullptr, 0, cw3, cb3, A, 96, nullptr, 8, 1);
    conv3x3<4><<<dim3(H_ / 2, 64 / 4, B_),  blk, 0, stream>>>(A, 96, nullptr, 0, cw4, cb4, Bf, 64, nullptr, 16, 1);
    conv3x3<4><<<dim3(H_ / 2, 32 / 4, B_),  blk, 0, stream>>>(Bf, 64, nullptr, 0, cw5, cb5, A, 32, nullptr, 1, 1);

    // final 32->2 conv, LeakyReLU, + flo residual (read+write d_out, same index per thread)
    conv3x3<2><<<dim3(H_ / 2, 1, B_), blk, 0, stream>>>(A, 32, nullptr, 0, cw6, cb6, outp, 2, outp, 1, 1);
}

// Round 2
// 2206.030 us; speedup vs baseline: 5.7317x; 5.7317x over previous
//
#include <hip/hip_runtime.h>
#include <hip/hip_bf16.h>

typedef _Float16 f16;
typedef __attribute__((ext_vector_type(8)))  _Float16 f16x8;
typedef __attribute__((ext_vector_type(4)))  _Float16 f16x4;
typedef __attribute__((ext_vector_type(16))) float    f32x16;

#define HW16K 16384

__device__ __forceinline__ void gld16(const void* g, void* l) {
    __builtin_amdgcn_global_load_lds((const __attribute__((address_space(1))) void*)g,
                                     (__attribute__((address_space(3))) void*)l, 16, 0, 0);
}

// ---------------------------------------------------------------------------
// Implicit-GEMM 3x3 conv via v_mfma_f32_32x32x16_f16.
// Activations NHWC f16 in spatially padded buffers [B][Ye][Xe][Cs].
// Block 256 (4 waves) = one (b, y) output row, 128 px, all Co (<=128).
// Wave w: pixels [32w, 32w+32). MF = CoPad/32 A-fragments per tap.
// B staged in LDS [3 rows][Wext][16ci] per 16-channel K-tile via global_load_lds.
// MODE 0: f16 NHWC store (+bias, LeakyReLU)
// MODE 1: flow head: fp32 store to d_out (NCHW) + f16 store to CC ch 32/33, no act
// MODE 2: final: +bias, LeakyReLU, += d_out (residual), store fp32 d_out
// ---------------------------------------------------------------------------
template <int DIL, int MF, int MODE>
__global__ __launch_bounds__(256) void conv_mfma(
    const f16* __restrict__ in, int inYe, int inXe, int inCs, int inPad,
    const f16* __restrict__ wp, const float* __restrict__ bias,
    f16* __restrict__ out, int outYe, int outXe, int outCs, int outPad, int outCoOff,
    float* __restrict__ dout,
    int Ci16, int CiPad, int CoPad)
{
    constexpr int Wext = 128 + 2 * DIL;
    constexpr int T    = 6 * Wext;          // 16B chunks: 3 rows * Wext px * 2 halves
    constexpr int TI   = (T + 255) / 256;
    __shared__ __align__(16) char smem[16384];

    const int tid  = threadIdx.x;
    const int lane = tid & 63;
    const int wv   = tid >> 6;
    const int col  = lane & 31;
    const int hi   = lane >> 5;
    const int xb   = wv * 32;
    const int y    = blockIdx.y;
    const int b    = blockIdx.z;
    const int ypad = y + inPad;

    const f16* inb = in + (size_t)b * inYe * inXe * inCs;

    f32x16 acc[MF] = {};

    for (int kt = 0; kt < Ci16; ++kt) {
        const int ci0 = kt * 16;
        // ---- stage B window into LDS (linear dest, per-lane global src) ----
#pragma unroll
        for (int i = 0; i < TI; ++i) {
            int c  = i * 256 + tid;
            int cc = (c < T) ? c : (T - 1);
            int row = cc / (2 * Wext);
            int rem = cc - row * (2 * Wext);
            int px = rem >> 1, half = rem & 1;
            const f16* src = inb
                + ((size_t)(ypad + (row - 1) * DIL) * inXe + (inPad - DIL + px)) * inCs
                + ci0 + half * 8;
            gld16(src, smem + c * 16);
        }
        __syncthreads();   // compiler drains vmcnt before s_barrier

        const f16* wk0 = wp + ci0 + hi * 8;
#pragma unroll
        for (int ky = 0; ky < 3; ++ky) {
#pragma unroll
            for (int kx = 0; kx < 3; ++kx) {
                const int wx = xb + col + kx * DIL;
                const f16x8 bfrag = *(const f16x8*)(smem + ((ky * Wext + wx) * 32 + hi * 16));
                const f16* wk = wk0 + (size_t)(ky * 3 + kx) * CoPad * CiPad;
#pragma unroll
                for (int m = 0; m < MF; ++m) {
                    f16x8 afrag = *(const f16x8*)(wk + (size_t)(32 * m + col) * CiPad);
                    acc[m] = __builtin_amdgcn_mfma_f32_32x32x16_f16(afrag, bfrag, acc[m], 0, 0, 0);
                }
            }
        }
        __syncthreads();
    }

    // ---- epilogue ----
    const int x = xb + col;
    if constexpr (MODE == 0) {
        const size_t pixbase =
            (((size_t)b * outYe + (y + outPad)) * outXe + (outPad + x)) * outCs + outCoOff;
#pragma unroll
        for (int m = 0; m < MF; ++m) {
#pragma unroll
            for (int q = 0; q < 4; ++q) {
                const int co = 32 * m + 8 * q + 4 * hi;
                f16x4 h;
#pragma unroll
                for (int s = 0; s < 4; ++s) {
                    float v = acc[m][4 * q + s] + bias[co + s];
                    v = (v >= 0.f) ? v : 0.1f * v;
                    h[s] = (f16)v;
                }
                *(f16x4*)(out + pixbase + co) = h;
            }
        }
    } else {
        if (hi == 0) {
#pragma unroll
            for (int s = 0; s < 2; ++s) {
                float v = acc[0][s] + bias[s];
                const size_t oi = (((size_t)b * 2 + s) * 128 + y) * 128 + x;
                if constexpr (MODE == 1) {
                    dout[oi] = v;
                    const size_t pixbase =
                        (((size_t)b * outYe + (y + outPad)) * outXe + (outPad + x)) * outCs + outCoOff;
                    out[pixbase + s] = (f16)v;
                } else {
                    v = (v >= 0.f) ? v : 0.1f * v;
                    dout[oi] += v;
                }
            }
        }
    }
}

// ---------------------------------------------------------------------------
// Correlation (fp32 math), writes f16 into IN0 channels 128..208 (NHWC, pad 1)
// ---------------------------------------------------------------------------
__global__ __launch_bounds__(256) void corr_nhwc(const float* __restrict__ x1,
                                                 const float* __restrict__ x2,
                                                 f16* __restrict__ in0) {
    const int x = threadIdx.x & 127;
    const int y = (blockIdx.x << 1) + (threadIdx.x >> 7);
    const int b = blockIdx.z;

    const float* p1 = x1 + (size_t)b * 128 * HW16K + y * 128 + x;
    const float* p2 = x2 + (size_t)b * 128 * HW16K;
    f16* orow = in0 + (((size_t)b * 130 + (y + 1)) * 130 + (x + 1)) * 224 + 128;

    for (int dy = 0; dy < 9; ++dy) {
        const int yy = y + dy - 4;
        float acc[9];
#pragma unroll
        for (int i = 0; i < 9; ++i) acc[i] = 0.f;
        if ((unsigned)yy < 128u) {
            for (int c = 0; c < 128; ++c) {
                const float v1 = p1[c * HW16K];
                const float* row = p2 + c * HW16K + yy * 128;
#pragma unroll
                for (int dx = 0; dx < 9; ++dx) {
                    const int xx = x + dx - 4;
                    const float v2 = ((unsigned)xx < 128u) ? row[xx] : 0.f;
                    acc[dx] = fmaf(v1, v2, acc[dx]);
                }
            }
        }
#pragma unroll
        for (int dx = 0; dx < 9; ++dx)
            orow[dy * 9 + dx] = (f16)(acc[dx] * (1.f / 128.f));
    }
}

// x1 fp32 NCHW -> IN0 NHWC f16 channels 0..127
__global__ __launch_bounds__(256) void x1_nhwc(const float* __restrict__ x1,
                                               f16* __restrict__ in0) {
    const int x = threadIdx.x & 127;
    const int y = (blockIdx.x << 1) + (threadIdx.x >> 7);
    const int b = blockIdx.z;
    const float* p1 = x1 + (size_t)b * 128 * HW16K + y * 128 + x;
    f16* o = in0 + (((size_t)b * 130 + (y + 1)) * 130 + (x + 1)) * 224;
    for (int c0 = 0; c0 < 128; c0 += 8) {
        f16x8 h;
#pragma unroll
        for (int j = 0; j < 8; ++j) h[j] = (f16)p1[(c0 + j) * HW16K];
        *(f16x8*)(o + c0) = h;
    }
}

__global__ void zero_border(f16* buf, int Ye, int Xe, int Cs, int pad) {
    const int cell = blockIdx.x * 256 + threadIdx.x;
    const int total = Ye * Xe;
    if (cell >= total) return;
    const int yy = cell / Xe, xx = cell - yy * Xe;
    if (yy >= pad && yy < Ye - pad && xx >= pad && xx < Xe - pad) return;
    f16* p = buf + ((size_t)blockIdx.z * Ye * Xe + cell) * Cs;
    f16x8 z = {};
    for (int c = 0; c < Cs; c += 8) *(f16x8*)(p + c) = z;
}

// fp32 OIHW -> f16 [tap][CoPad][CiPad], zero-padded
__global__ void prepack(const float* __restrict__ w, f16* __restrict__ wp,
                        int Co, int Ci, int CoPad, int CiPad) {
    const size_t i = (size_t)blockIdx.x * 256 + threadIdx.x;
    const size_t total = (size_t)9 * CoPad * CiPad;
    if (i >= total) return;
    const int k  = (int)(i / ((size_t)CoPad * CiPad));
    const int r  = (int)(i - (size_t)k * CoPad * CiPad);
    const int co = r / CiPad;
    const int ci = r - co * CiPad;
    f16 v = (f16)0.f;
    if (co < Co && ci < Ci) v = (f16)w[((size_t)co * Ci + ci) * 9 + k];
    wp[i] = v;
}

extern "C" void kernel_launch(void* const* d_in, const int* in_sizes, int n_in,
                              void* d_out, int out_size, void* d_ws, size_t ws_size,
                              hipStream_t stream) {
    const float* x1 = (const float*)d_in[0];
    const float* x2 = (const float*)d_in[1];
    const float* W[13]  = {(const float*)d_in[2],  (const float*)d_in[4],  (const float*)d_in[6],
                           (const float*)d_in[8],  (const float*)d_in[10], (const float*)d_in[12],
                           (const float*)d_in[14], (const float*)d_in[16], (const float*)d_in[18],
                           (const float*)d_in[20], (const float*)d_in[22], (const float*)d_in[24],
                           (const float*)d_in[26]};
    const float* Bs[13] = {(const float*)d_in[3],  (const float*)d_in[5],  (const float*)d_in[7],
                           (const float*)d_in[9],  (const float*)d_in[11], (const float*)d_in[13],
                           (const float*)d_in[15], (const float*)d_in[17], (const float*)d_in[19],
                           (const float*)d_in[21], (const float*)d_in[23], (const float*)d_in[25],
                           (const float*)d_in[27]};
    float* outp = (float*)d_out;

    // ---- workspace layout (bytes) ----
    char* ws = (char*)d_ws;
    f16* IN0 = (f16*)(ws);                       // [8][130][130][224] = 60,569,600 B
    f16* P   = (f16*)(ws + 60569600);            // [8][144][144][128] = 42,467,328 B
    f16* Q   = (f16*)(ws + 103036928);           // [8][160][160][128] = 52,428,800 B
    f16* CC  = (f16*)(ws + 155465728);           // [8][130][130][64]  = 17,305,600 B
    char* WPB = ws + 172771328;

    // per-layer: {Co, Ci, CoPad, CiPad}
    const int LC[13][4] = {
        {128, 209, 128, 224}, {128, 128, 128, 128}, {96, 128, 96, 128},
        {64, 96, 64, 96},     {32, 64, 32, 64},     {2, 32, 32, 32},
        {128, 34, 128, 64},   {128, 128, 128, 128}, {128, 128, 128, 128},
        {96, 128, 96, 128},   {64, 96, 64, 96},     {32, 64, 32, 64},
        {2, 32, 32, 32}};
    f16* wpp[13];
    {
        size_t off = 0;
        for (int l = 0; l < 13; ++l) {
            wpp[l] = (f16*)(WPB + off);
            off += (size_t)9 * LC[l][2] * LC[l][3] * 2;
        }
    }

    const dim3 blk(256, 1, 1);

    // ---- prepack weights ----
    for (int l = 0; l < 13; ++l) {
        const int total = 9 * LC[l][2] * LC[l][3];
        prepack<<<dim3((total + 255) / 256, 1, 1), blk, 0, stream>>>(
            W[l], wpp[l], LC[l][0], LC[l][1], LC[l][2], LC[l][3]);
    }
    // ---- zero borders ----
    zero_border<<<dim3((130 * 130 + 255) / 256, 1, 8), blk, 0, stream>>>(IN0, 130, 130, 224, 1);
    zero_border<<<dim3((144 * 144 + 255) / 256, 1, 8), blk, 0, stream>>>(P, 144, 144, 128, 8);
    zero_border<<<dim3((160 * 160 + 255) / 256, 1, 8), blk, 0, stream>>>(Q, 160, 160, 128, 16);
    zero_border<<<dim3((130 * 130 + 255) / 256, 1, 8), blk, 0, stream>>>(CC, 130, 130, 64, 1);

    // ---- inputs -> NHWC f16 ----
    x1_nhwc<<<dim3(64, 1, 8), blk, 0, stream>>>(x1, IN0);
    corr_nhwc<<<dim3(64, 1, 8), blk, 0, stream>>>(x1, x2, IN0);

    const dim3 cg(1, 128, 8);
    // ---- flow estimator ----
    conv_mfma<1, 4, 0><<<cg, blk, 0, stream>>>(IN0, 130, 130, 224, 1, wpp[0], Bs[0],
                                               P, 144, 144, 128, 8, 0, nullptr, 14, 224, 128);
    conv_mfma<1, 4, 0><<<cg, blk, 0, stream>>>(P, 144, 144, 128, 8, wpp[1], Bs[1],
                                               Q, 160, 160, 128, 16, 0, nullptr, 8, 128, 128);
    conv_mfma<1, 3, 0><<<cg, blk, 0, stream>>>(Q, 160, 160, 128, 16, wpp[2], Bs[2],
                                               P, 144, 144, 128, 8, 0, nullptr, 8, 128, 96);
    conv_mfma<1, 2, 0><<<cg, blk, 0, stream>>>(P, 144, 144, 128, 8, wpp[3], Bs[3],
                                               Q, 160, 160, 128, 16, 0, nullptr, 6, 96, 64);
    conv_mfma<1, 1, 0><<<cg, blk, 0, stream>>>(Q, 160, 160, 128, 16, wpp[4], Bs[4],
                                               CC, 130, 130, 64, 1, 0, nullptr, 4, 64, 32);
    // flow head: reads CC ch 0..31, writes d_out fp32 + CC ch 32/33
    conv_mfma<1, 1, 1><<<cg, blk, 0, stream>>>(CC, 130, 130, 64, 1, wpp[5], Bs[5],
                                               CC, 130, 130, 64, 1, 32, outp, 2, 32, 32);
    // ---- context network ----
    conv_mfma<1, 4, 0><<<cg, blk, 0, stream>>>(CC, 130, 130, 64, 1, wpp[6], Bs[6],
                                               P, 144, 144, 128, 8, 0, nullptr, 4, 64, 128);
    conv_mfma<2, 4, 0><<<cg, blk, 0, stream>>>(P, 144, 144, 128, 8, wpp[7], Bs[7],
                                               Q, 160, 160, 128, 16, 0, nullptr, 8, 128, 128);
    conv_mfma<4, 4, 0><<<cg, blk, 0, stream>>>(Q, 160, 160, 128, 16, wpp[8], Bs[8],
                                               P, 144, 144, 128, 8, 0, nullptr, 8, 128, 128);
    conv_mfma<8, 3, 0><<<cg, blk, 0, stream>>>(P, 144, 144, 128, 8, wpp[9], Bs[9],
                                               Q, 160, 160, 128, 16, 0, nullptr, 8, 128, 96);
    conv_mfma<16, 2, 0><<<cg, blk, 0, stream>>>(Q, 160, 160, 128, 16, wpp[10], Bs[10],
                                                P, 144, 144, 128, 8, 0, nullptr, 6, 96, 64);
    conv_mfma<1, 1, 0><<<cg, blk, 0, stream>>>(P, 144, 144, 128, 8, wpp[11], Bs[11],
                                               Q, 160, 160, 128, 16, 0, nullptr, 4, 64, 32);
    // final: 32->2, leaky, += flo (d_out)
    conv_mfma<1, 1, 2><<<cg, blk, 0, stream>>>(Q, 160, 160, 128, 16, wpp[12], Bs[12],
                                               nullptr, 0, 0, 0, 0, 0, outp, 2, 32, 32);
}

// Round 4
// 1384.661 us; speedup vs baseline: 9.1316x; 1.5932x over previous
//
#include <hip/hip_runtime.h>
#include <hip/hip_bf16.h>

typedef _Float16 f16;
typedef __attribute__((ext_vector_type(8)))  _Float16 f16x8;
typedef __attribute__((ext_vector_type(4)))  _Float16 f16x4;
typedef __attribute__((ext_vector_type(16))) float    f32x16;

#define HW16K 16384

__device__ __forceinline__ void gld16(const void* g, void* l) {
    __builtin_amdgcn_global_load_lds((const __attribute__((address_space(1))) void*)g,
                                     (__attribute__((address_space(3))) void*)l, 16, 0, 0);
}

// ---------------------------------------------------------------------------
// Implicit-GEMM 3x3 conv via v_mfma_f32_32x32x16_f16.  (round-3 version,
// kept unchanged for bisection)
// NHWC f16 activations in spatially padded buffers [B][Ye][Xe][Cs].
// Block 512 (8 waves) = 2 output rows x 128 px, all Co (<=128).
// Wave w: row t=w>>2, pixels [(w&3)*32, +32). MF = CoPad/32 A-frags per tap.
// 2-phase pipeline: stage K-tile kt+1 (global_load_lds) before computing kt.
// ---------------------------------------------------------------------------
template <int DIL, int MF, int MODE>
__global__ __launch_bounds__(512) void conv_mfma(
    const f16* __restrict__ in, int inYe, int inXe, int inCs, int inPad,
    const f16* __restrict__ wp, const float* __restrict__ bias,
    f16* __restrict__ out, int outYe, int outXe, int outCs, int outPad, int outCoOff,
    float* __restrict__ dout,
    int Ci16, int CiPad, int CoPad)
{
    constexpr int Wext = 128 + 2 * DIL;
    constexpr int NR   = (DIL == 1) ? 4 : 6;
    constexpr int CH   = NR * Wext * 2;        // 16B chunks per K-tile
    constexpr int CHB  = CH * 16;
    constexpr int TI   = (CH + 511) / 512;
    __shared__ __align__(16) char smem[2 * CHB];

    const int tid  = threadIdx.x;
    const int lane = tid & 63;
    const int wv   = tid >> 6;
    const int col  = lane & 31;
    const int hi   = lane >> 5;
    const int t    = wv >> 2;        // output row within block
    const int xb   = (wv & 3) * 32;

    const int g  = blockIdx.x;                 // XCD-swizzled (b, ychunk)
    const int n  = (g & 7) * 64 + (g >> 3);
    const int b  = n >> 6;
    const int y0 = (n & 63) * 2;

    const f16* inb = in + (size_t)b * inYe * inXe * inCs;

    auto stage = [&](int kt, int bufi) {
        const int ci0 = kt * 16;
        char* sb = smem + bufi * CHB;
#pragma unroll
        for (int i = 0; i < TI; ++i) {
            int c = i * 512 + tid;
            if (c < CH) {
                int r   = c / (Wext * 2);
                int rem = c - r * (Wext * 2);
                int px = rem >> 1, half = rem & 1;
                int yin = (DIL == 1) ? (y0 - 1 + r)
                                     : (y0 + (r & 1) + ((r >> 1) - 1) * DIL);
                const f16* src = inb
                    + ((size_t)(yin + inPad) * inXe + (inPad - DIL + px)) * inCs
                    + ci0 + half * 8;
                gld16(src, sb + c * 16);
            }
        }
    };

    f32x16 acc[MF] = {};

    stage(0, 0);
    __syncthreads();
    for (int kt = 0; kt < Ci16; ++kt) {
        if (kt + 1 < Ci16) stage(kt + 1, (kt + 1) & 1);
        const char* sb = smem + (kt & 1) * CHB;
        const f16* wk0 = wp + kt * 16 + hi * 8;
#pragma unroll
        for (int ky = 0; ky < 3; ++ky) {
#pragma unroll
            for (int kx = 0; kx < 3; ++kx) {
                const int r = (DIL == 1) ? (t + ky) : (ky * 2 + t);
                const f16x8 bfrag =
                    *(const f16x8*)(sb + ((r * Wext + xb + col + kx * DIL) * 32 + hi * 16));
                const f16* wk = wk0 + (size_t)(ky * 3 + kx) * CoPad * CiPad;
#pragma unroll
                for (int m = 0; m < MF; ++m) {
                    f16x8 afrag = *(const f16x8*)(wk + (size_t)(32 * m + col) * CiPad);
                    acc[m] = __builtin_amdgcn_mfma_f32_32x32x16_f16(afrag, bfrag, acc[m], 0, 0, 0);
                }
            }
        }
        __syncthreads();
    }

    // ---- epilogue ----
    const int x = xb + col;
    const int y = y0 + t;
    if constexpr (MODE == 0) {
        const size_t pixbase =
            (((size_t)b * outYe + (y + outPad)) * outXe + (outPad + x)) * outCs + outCoOff;
#pragma unroll
        for (int m = 0; m < MF; ++m) {
#pragma unroll
            for (int q = 0; q < 4; ++q) {
                const int co = 32 * m + 8 * q + 4 * hi;
                f16x4 h;
#pragma unroll
                for (int s = 0; s < 4; ++s) {
                    float v = acc[m][4 * q + s] + bias[co + s];
                    v = (v >= 0.f) ? v : 0.1f * v;
                    h[s] = (f16)v;
                }
                *(f16x4*)(out + pixbase + co) = h;
            }
        }
    } else {
        if (hi == 0) {
#pragma unroll
            for (int s = 0; s < 2; ++s) {
                float v = acc[0][s] + bias[s];
                const size_t oi = (((size_t)b * 2 + s) * 128 + y) * 128 + x;
                if constexpr (MODE == 1) {
                    dout[oi] = v;
                    const size_t pixbase =
                        (((size_t)b * outYe + (y + outPad)) * outXe + (outPad + x)) * outCs + outCoOff;
                    out[pixbase + s] = (f16)v;
                } else {
                    v = (v >= 0.f) ? v : 0.1f * v;
                    dout[oi] += v;
                }
            }
        }
    }
}

// ---------------------------------------------------------------------------
// Correlation: round-2-proven fp32 direct-read body. Scalar float loads only.
// Grid (512 swizzled, 3): blockIdx.y selects a group of 3 dy values
// (occupancy 25% -> 75%); per-thread math identical to the passing round-2
// kernel. Writes f16 into IN0 channels 128..208 (NHWC, pad 1).
// ---------------------------------------------------------------------------
__global__ __launch_bounds__(256) void corr_nhwc(const float* __restrict__ x1,
                                                 const float* __restrict__ x2,
                                                 f16* __restrict__ in0) {
    const int g = blockIdx.x;                  // bijective XCD swizzle
    const int n = (g & 7) * 64 + (g >> 3);
    const int b = n >> 6;
    const int x = threadIdx.x & 127;
    const int y = (n & 63) * 2 + (threadIdx.x >> 7);
    const int dy0 = blockIdx.y * 3;

    const float* p1 = x1 + (size_t)b * 128 * HW16K + y * 128 + x;
    const float* p2 = x2 + (size_t)b * 128 * HW16K;
    f16* orow = in0 + (((size_t)b * 130 + (y + 1)) * 130 + (x + 1)) * 224 + 128;

    for (int dy = dy0; dy < dy0 + 3; ++dy) {
        const int yy = y + dy - 4;
        float acc[9];
#pragma unroll
        for (int i = 0; i < 9; ++i) acc[i] = 0.f;
        if ((unsigned)yy < 128u) {
            for (int c = 0; c < 128; ++c) {
                const float v1 = p1[c * HW16K];
                const float* row = p2 + c * HW16K + yy * 128;
#pragma unroll
                for (int dx = 0; dx < 9; ++dx) {
                    const int xx = x + dx - 4;
                    const float v2 = ((unsigned)xx < 128u) ? row[xx] : 0.f;
                    acc[dx] = fmaf(v1, v2, acc[dx]);
                }
            }
        }
#pragma unroll
        for (int dx = 0; dx < 9; ++dx)
            orow[dy * 9 + dx] = (f16)(acc[dx] * (1.f / 128.f));
    }
}

// x1 fp32 NCHW -> IN0 NHWC f16 channels 0..127 (round-2 version)
__global__ __launch_bounds__(256) void x1_nhwc(const float* __restrict__ x1,
                                               f16* __restrict__ in0) {
    const int x = threadIdx.x & 127;
    const int y = blockIdx.x * 2 + (threadIdx.x >> 7);
    const int b = blockIdx.z;
    const float* p1 = x1 + (size_t)b * 128 * HW16K + y * 128 + x;
    f16* o = in0 + (((size_t)b * 130 + (y + 1)) * 130 + (x + 1)) * 224;
    for (int c0 = 0; c0 < 128; c0 += 8) {
        f16x8 h;
#pragma unroll
        for (int j = 0; j < 8; ++j) h[j] = (f16)p1[(c0 + j) * HW16K];
        *(f16x8*)(o + c0) = h;
    }
}

__global__ void zero_border(f16* buf, int Ye, int Xe, int Cs, int pad) {
    const int cell = blockIdx.x * 256 + threadIdx.x;
    const int total = Ye * Xe;
    if (cell >= total) return;
    const int yy = cell / Xe, xx = cell - yy * Xe;
    if (yy >= pad && yy < Ye - pad && xx >= pad && xx < Xe - pad) return;
    f16* p = buf + ((size_t)blockIdx.z * Ye * Xe + cell) * Cs;
    f16x8 z = {};
    for (int c = 0; c < Cs; c += 8) *(f16x8*)(p + c) = z;
}

// all 13 weight tensors: fp32 OIHW -> f16 [tap][CoPad][CiPad], zero-padded
struct PPA {
    const float* src[13];
    f16* dst[13];
    int Co[13], Ci[13], CoPad[13], CiPad[13];
};
__global__ void prepack_all(PPA a) {
    const int l = blockIdx.z;
    const int CoPad = a.CoPad[l], CiPad = a.CiPad[l];
    const int total = 9 * CoPad * CiPad;
    const int i = blockIdx.x * 256 + threadIdx.x;
    if (i >= total) return;
    const int k  = i / (CoPad * CiPad);
    const int r  = i - k * CoPad * CiPad;
    const int co = r / CiPad;
    const int ci = r - co * CiPad;
    f16 v = (f16)0.f;
    if (co < a.Co[l] && ci < a.Ci[l])
        v = (f16)a.src[l][((size_t)co * a.Ci[l] + ci) * 9 + k];
    a.dst[l][i] = v;
}

extern "C" void kernel_launch(void* const* d_in, const int* in_sizes, int n_in,
                              void* d_out, int out_size, void* d_ws, size_t ws_size,
                              hipStream_t stream) {
    const float* x1 = (const float*)d_in[0];
    const float* x2 = (const float*)d_in[1];
    const float* W[13]  = {(const float*)d_in[2],  (const float*)d_in[4],  (const float*)d_in[6],
                           (const float*)d_in[8],  (const float*)d_in[10], (const float*)d_in[12],
                           (const float*)d_in[14], (const float*)d_in[16], (const float*)d_in[18],
                           (const float*)d_in[20], (const float*)d_in[22], (const float*)d_in[24],
                           (const float*)d_in[26]};
    const float* Bs[13] = {(const float*)d_in[3],  (const float*)d_in[5],  (const float*)d_in[7],
                           (const float*)d_in[9],  (const float*)d_in[11], (const float*)d_in[13],
                           (const float*)d_in[15], (const float*)d_in[17], (const float*)d_in[19],
                           (const float*)d_in[21], (const float*)d_in[23], (const float*)d_in[25],
                           (const float*)d_in[27]};
    float* outp = (float*)d_out;

    // ---- workspace layout (bytes) ----
    char* ws = (char*)d_ws;
    f16* IN0 = (f16*)(ws);                       // [8][130][130][224] = 60,569,600 B
    f16* P   = (f16*)(ws + 60569600);            // [8][144][144][128] = 42,467,328 B
    f16* Q   = (f16*)(ws + 103036928);           // [8][160][160][128] = 52,428,800 B
    f16* CC  = (f16*)(ws + 155465728);           // [8][130][130][64]  = 17,305,600 B
    char* WPB = ws + 172771328;

    // per-layer: {Co, Ci, CoPad, CiPad}
    const int LC[13][4] = {
        {128, 209, 128, 224}, {128, 128, 128, 128}, {96, 128, 96, 128},
        {64, 96, 64, 96},     {32, 64, 32, 64},     {2, 32, 32, 32},
        {128, 34, 128, 64},   {128, 128, 128, 128}, {128, 128, 128, 128},
        {96, 128, 96, 128},   {64, 96, 64, 96},     {32, 64, 32, 64},
        {2, 32, 32, 32}};
    f16* wpp[13];
    PPA pa;
    {
        size_t off = 0;
        for (int l = 0; l < 13; ++l) {
            wpp[l] = (f16*)(WPB + off);
            off += (size_t)9 * LC[l][2] * LC[l][3] * 2;
            pa.src[l] = W[l]; pa.dst[l] = wpp[l];
            pa.Co[l] = LC[l][0]; pa.Ci[l] = LC[l][1];
            pa.CoPad[l] = LC[l][2]; pa.CiPad[l] = LC[l][3];
        }
    }

    const dim3 blk(256, 1, 1);
    const dim3 blk512(512, 1, 1);

    // weights (single fused launch) + all borders up front
    prepack_all<<<dim3(1008, 1, 13), blk, 0, stream>>>(pa);
    zero_border<<<dim3(67, 1, 8),  blk, 0, stream>>>(IN0, 130, 130, 224, 1);
    zero_border<<<dim3(67, 1, 8),  blk, 0, stream>>>(CC, 130, 130, 64, 1);
    zero_border<<<dim3(81, 1, 8),  blk, 0, stream>>>(P, 144, 144, 128, 8);
    zero_border<<<dim3(100, 1, 8), blk, 0, stream>>>(Q, 160, 160, 128, 16);

    // inputs -> NHWC f16 ; correlation (fp32 reads, dy-split grid)
    x1_nhwc<<<dim3(64, 1, 8), blk, 0, stream>>>(x1, IN0);
    corr_nhwc<<<dim3(512, 3, 1), blk, 0, stream>>>(x1, x2, IN0);

    const dim3 cg(512, 1, 1);
    // ---- flow estimator ----
    conv_mfma<1, 4, 0><<<cg, blk512, 0, stream>>>(IN0, 130, 130, 224, 1, wpp[0], Bs[0],
                                                  P, 144, 144, 128, 8, 0, nullptr, 14, 224, 128);
    conv_mfma<1, 4, 0><<<cg, blk512, 0, stream>>>(P, 144, 144, 128, 8, wpp[1], Bs[1],
                                                  Q, 160, 160, 128, 16, 0, nullptr, 8, 128, 128);
    conv_mfma<1, 3, 0><<<cg, blk512, 0, stream>>>(Q, 160, 160, 128, 16, wpp[2], Bs[2],
                                                  P, 144, 144, 128, 8, 0, nullptr, 8, 128, 96);
    conv_mfma<1, 2, 0><<<cg, blk512, 0, stream>>>(P, 144, 144, 128, 8, wpp[3], Bs[3],
                                                  Q, 160, 160, 128, 16, 0, nullptr, 6, 96, 64);
    conv_mfma<1, 1, 0><<<cg, blk512, 0, stream>>>(Q, 160, 160, 128, 16, wpp[4], Bs[4],
                                                  CC, 130, 130, 64, 1, 0, nullptr, 4, 64, 32);
    // flow head: reads CC ch0..31, writes d_out fp32 + CC ch32/33
    conv_mfma<1, 1, 1><<<cg, blk512, 0, stream>>>(CC, 130, 130, 64, 1, wpp[5], Bs[5],
                                                  CC, 130, 130, 64, 1, 32, outp, 2, 32, 32);
    // ---- context network ----
    conv_mfma<1, 4, 0><<<cg, blk512, 0, stream>>>(CC, 130, 130, 64, 1, wpp[6], Bs[6],
                                                  P, 144, 144, 128, 8, 0, nullptr, 4, 64, 128);
    conv_mfma<2, 4, 0><<<cg, blk512, 0, stream>>>(P, 144, 144, 128, 8, wpp[7], Bs[7],
                                                  Q, 160, 160, 128, 16, 0, nullptr, 8, 128, 128);
    conv_mfma<4, 4, 0><<<cg, blk512, 0, stream>>>(Q, 160, 160, 128, 16, wpp[8], Bs[8],
                                                  P, 144, 144, 128, 8, 0, nullptr, 8, 128, 128);
    conv_mfma<8, 3, 0><<<cg, blk512, 0, stream>>>(P, 144, 144, 128, 8, wpp[9], Bs[9],
                                                  Q, 160, 160, 128, 16, 0, nullptr, 8, 128, 96);
    conv_mfma<16, 2, 0><<<cg, blk512, 0, stream>>>(Q, 160, 160, 128, 16, wpp[10], Bs[10],
                                                   P, 144, 144, 128, 8, 0, nullptr, 6, 96, 64);
    conv_mfma<1, 1, 0><<<cg, blk512, 0, stream>>>(P, 144, 144, 128, 8, wpp[11], Bs[11],
                                                  Q, 160, 160, 128, 16, 0, nullptr, 4, 64, 32);
    // final: 32->2, leaky, += flo (d_out)
    conv_mfma<1, 1, 2><<<cg, blk512, 0, stream>>>(Q, 160, 160, 128, 16, wpp[12], Bs[12],
                                                  nullptr, 0, 0, 0, 0, 0, outp, 2, 32, 32);
}

// Round 5
// 834.748 us; speedup vs baseline: 15.1474x; 1.6588x over previous
//
#include <hip/hip_runtime.h>
#include <hip/hip_bf16.h>

typedef _Float16 f16;
typedef __attribute__((ext_vector_type(2)))  _Float16 h2;
typedef __attribute__((ext_vector_type(8)))  _Float16 f16x8;
typedef __attribute__((ext_vector_type(4)))  _Float16 f16x4;
typedef __attribute__((ext_vector_type(16))) float    f32x16;

#define HW16K 16384

__device__ __forceinline__ void gld16(const void* g, void* l) {
    __builtin_amdgcn_global_load_lds((const __attribute__((address_space(1))) void*)g,
                                     (__attribute__((address_space(3))) void*)l, 16, 0, 0);
}

// ---------------------------------------------------------------------------
// Implicit-GEMM 3x3 conv via v_mfma_f32_32x32x16_f16.
// NHWC f16 activations in spatially padded buffers [B][Ye][Xe][Cs].
// Block 512 (8 waves) = 2 output rows x 128 px, all Co (<=128).
// Wave w: row t=w>>2, pixels [(w&3)*32, +32). MF = CoPad/32 A-frags per tap.
// 2-phase pipeline: stage K-tile kt+1 (global_load_lds) before computing kt.
// Weights prepacked [kt][tap][CoPad][16] -> contiguous per-K-tile reads.
// ---------------------------------------------------------------------------
template <int DIL, int MF, int MODE>
__global__ __launch_bounds__(512) void conv_mfma(
    const f16* __restrict__ in, int inYe, int inXe, int inCs, int inPad,
    const f16* __restrict__ wp, const float* __restrict__ bias,
    f16* __restrict__ out, int outYe, int outXe, int outCs, int outPad, int outCoOff,
    float* __restrict__ dout,
    int Ci16, int CiPad, int CoPad)
{
    constexpr int Wext = 128 + 2 * DIL;
    constexpr int NR   = (DIL == 1) ? 4 : 6;
    constexpr int CH   = NR * Wext * 2;        // 16B chunks per K-tile
    constexpr int CHB  = CH * 16;
    constexpr int TI   = (CH + 511) / 512;
    __shared__ __align__(16) char smem[2 * CHB];

    const int tid  = threadIdx.x;
    const int lane = tid & 63;
    const int wv   = tid >> 6;
    const int col  = lane & 31;
    const int hi   = lane >> 5;
    const int t    = wv >> 2;        // output row within block
    const int xb   = (wv & 3) * 32;

    const int g  = blockIdx.x;                 // XCD-swizzled (b, ychunk)
    const int n  = (g & 7) * 64 + (g >> 3);
    const int b  = n >> 6;
    const int y0 = (n & 63) * 2;

    const f16* inb = in + (size_t)b * inYe * inXe * inCs;

    auto stage = [&](int kt, int bufi) {
        const int ci0 = kt * 16;
        char* sb = smem + bufi * CHB;
#pragma unroll
        for (int i = 0; i < TI; ++i) {
            int c = i * 512 + tid;
            if (c < CH) {
                int r   = c / (Wext * 2);
                int rem = c - r * (Wext * 2);
                int px = rem >> 1, half = rem & 1;
                int yin = (DIL == 1) ? (y0 - 1 + r)
                                     : (y0 + (r & 1) + ((r >> 1) - 1) * DIL);
                const f16* src = inb
                    + ((size_t)(yin + inPad) * inXe + (inPad - DIL + px)) * inCs
                    + ci0 + half * 8;
                gld16(src, sb + c * 16);
            }
        }
    };

    f32x16 acc[MF] = {};

    stage(0, 0);
    __syncthreads();
    for (int kt = 0; kt < Ci16; ++kt) {
        if (kt + 1 < Ci16) stage(kt + 1, (kt + 1) & 1);
        const char* sb = smem + (kt & 1) * CHB;
        const f16* wkt = wp + (size_t)kt * 9 * CoPad * 16 + hi * 8;
#pragma unroll
        for (int ky = 0; ky < 3; ++ky) {
#pragma unroll
            for (int kx = 0; kx < 3; ++kx) {
                const int r = (DIL == 1) ? (t + ky) : (ky * 2 + t);
                const f16x8 bfrag =
                    *(const f16x8*)(sb + ((r * Wext + xb + col + kx * DIL) * 32 + hi * 16));
                const f16* wtap = wkt + (size_t)(ky * 3 + kx) * CoPad * 16;
#pragma unroll
                for (int m = 0; m < MF; ++m) {
                    f16x8 afrag = *(const f16x8*)(wtap + (32 * m + col) * 16);
                    acc[m] = __builtin_amdgcn_mfma_f32_32x32x16_f16(afrag, bfrag, acc[m], 0, 0, 0);
                }
            }
        }
        __syncthreads();
    }

    // ---- epilogue ----
    const int x = xb + col;
    const int y = y0 + t;
    if constexpr (MODE == 0) {
        const size_t pixbase =
            (((size_t)b * outYe + (y + outPad)) * outXe + (outPad + x)) * outCs + outCoOff;
#pragma unroll
        for (int m = 0; m < MF; ++m) {
#pragma unroll
            for (int q = 0; q < 4; ++q) {
                const int co = 32 * m + 8 * q + 4 * hi;
                f16x4 h;
#pragma unroll
                for (int s = 0; s < 4; ++s) {
                    float v = acc[m][4 * q + s] + bias[co + s];
                    v = (v >= 0.f) ? v : 0.1f * v;
                    h[s] = (f16)v;
                }
                *(f16x4*)(out + pixbase + co) = h;
            }
        }
    } else {
        if (hi == 0) {
#pragma unroll
            for (int s = 0; s < 2; ++s) {
                float v = acc[0][s] + bias[s];
                const size_t oi = (((size_t)b * 2 + s) * 128 + y) * 128 + x;
                if constexpr (MODE == 1) {
                    dout[oi] = v;
                    const size_t pixbase =
                        (((size_t)b * outYe + (y + outPad)) * outXe + (outPad + x)) * outCs + outCoOff;
                    out[pixbase + s] = (f16)v;
                } else {
                    v = (v >= 0.f) ? v : 0.1f * v;
                    dout[oi] += v;
                }
            }
        }
    }
}

// ---------------------------------------------------------------------------
// Correlation v3: channel-pair f16 layouts + v_dot2_f32_f16, SCALAR 4B loads
// only (bisects round-3's 16B-cast UB). dy split over blockIdx.y (3 each).
// PX1: [b][64][128][128][2]   PX2: [b][64][136][136][2] (4-px zero border)
// Writes f16 into IN0 channels 128..208.
// ---------------------------------------------------------------------------
__global__ __launch_bounds__(256) void corr_k(const h2* __restrict__ px1,
                                              const h2* __restrict__ px2,
                                              f16* __restrict__ in0) {
    const int g = blockIdx.x;                  // bijective XCD swizzle
    const int n = (g & 7) * 64 + (g >> 3);
    const int b = n >> 6;
    const int x = threadIdx.x & 127;
    const int y = (n & 63) * 2 + (threadIdx.x >> 7);
    const int dy0 = blockIdx.y * 3;

    const h2* p1  = px1 + (size_t)b * 64 * HW16K + y * 128 + x;
    const h2* p2b = px2 + (size_t)b * 64 * 18496 + (size_t)(y + dy0) * 136 + x;
    f16* orow = in0 + (((size_t)b * 130 + (y + 1)) * 130 + (x + 1)) * 224 + 128;

    float acc[3][9] = {};
    for (int cp = 0; cp < 64; ++cp) {
        const h2 v1 = p1[(size_t)cp * HW16K];
        const h2* rows = p2b + (size_t)cp * 18496;
#pragma unroll
        for (int j = 0; j < 3; ++j) {
            const h2* row = rows + j * 136;
#pragma unroll
            for (int d = 0; d < 9; ++d)
                acc[j][d] = __builtin_amdgcn_fdot2(v1, row[d], acc[j][d], false);
        }
    }
#pragma unroll
    for (int j = 0; j < 3; ++j)
#pragma unroll
        for (int d = 0; d < 9; ++d)
            orow[(dy0 + j) * 9 + d] = (f16)(acc[j][d] * (1.f / 128.f));
}

// x1 fp32 NCHW -> IN0 NHWC ch0..127 AND PX1 channel-pair layout
__global__ __launch_bounds__(256) void x1pack(const float* __restrict__ x1,
                                              f16* __restrict__ in0,
                                              h2* __restrict__ px1) {
    const int x = threadIdx.x & 127;
    const int y = blockIdx.x * 2 + (threadIdx.x >> 7);
    const int b = blockIdx.z;
    const float* p1 = x1 + (size_t)b * 128 * HW16K + y * 128 + x;
    f16* o = in0 + (((size_t)b * 130 + (y + 1)) * 130 + (x + 1)) * 224;
    h2* q = px1 + (size_t)b * 64 * HW16K + y * 128 + x;
    for (int cp = 0; cp < 64; ++cp) {
        const float a0 = p1[(2 * cp) * HW16K];
        const float a1 = p1[(2 * cp + 1) * HW16K];
        h2 v; v[0] = (f16)a0; v[1] = (f16)a1;
        q[(size_t)cp * HW16K] = v;
        *(h2*)(o + 2 * cp) = v;
    }
}

// x2 fp32 NCHW -> PX2 padded channel-pair layout (writes zeros in border)
__global__ __launch_bounds__(256) void x2pack(const float* __restrict__ x2,
                                              h2* __restrict__ px2) {
    const int cell = blockIdx.x * 256 + threadIdx.x;   // over 136x136
    if (cell >= 136 * 136) return;
    const int yp = cell / 136, xp = cell - yp * 136;
    const int cp = blockIdx.y, b = blockIdx.z;
    h2 v; v[0] = (f16)0.f; v[1] = (f16)0.f;
    const int yy = yp - 4, xx = xp - 4;
    if ((unsigned)yy < 128u && (unsigned)xx < 128u) {
        const float* p = x2 + (size_t)b * 128 * HW16K + (2 * cp) * HW16K + yy * 128 + xx;
        v[0] = (f16)p[0];
        v[1] = (f16)p[HW16K];
    }
    px2[((size_t)(b * 64 + cp) * 136 + yp) * 136 + xp] = v;
}

__global__ void zero_border(f16* buf, int Ye, int Xe, int Cs, int pad) {
    const int cell = blockIdx.x * 256 + threadIdx.x;
    const int total = Ye * Xe;
    if (cell >= total) return;
    const int yy = cell / Xe, xx = cell - yy * Xe;
    if (yy >= pad && yy < Ye - pad && xx >= pad && xx < Xe - pad) return;
    f16* p = buf + ((size_t)blockIdx.z * Ye * Xe + cell) * Cs;
    f16x8 z = {};
    for (int c = 0; c < Cs; c += 8) *(f16x8*)(p + c) = z;
}

// all 13 weight tensors: fp32 OIHW -> f16 [kt][tap][CoPad][16], zero-padded
struct PPA {
    const float* src[13];
    f16* dst[13];
    int Co[13], Ci[13], CoPad[13], CiPad[13];
};
__global__ void prepack_all(PPA a) {
    const int l = blockIdx.z;
    const int CoPad = a.CoPad[l], CiPad = a.CiPad[l];
    const int total = 9 * CoPad * CiPad;
    const int i = blockIdx.x * 256 + threadIdx.x;
    if (i >= total) return;
    const int k  = i / (CoPad * CiPad);
    const int r  = i - k * CoPad * CiPad;
    const int co = r / CiPad;
    const int ci = r - co * CiPad;
    f16 v = (f16)0.f;
    if (co < a.Co[l] && ci < a.Ci[l])
        v = (f16)a.src[l][((size_t)co * a.Ci[l] + ci) * 9 + k];
    const int kt = ci >> 4, cin = ci & 15;
    a.dst[l][(((size_t)kt * 9 + k) * CoPad + co) * 16 + cin] = v;
}

extern "C" void kernel_launch(void* const* d_in, const int* in_sizes, int n_in,
                              void* d_out, int out_size, void* d_ws, size_t ws_size,
                              hipStream_t stream) {
    const float* x1 = (const float*)d_in[0];
    const float* x2 = (const float*)d_in[1];
    const float* W[13]  = {(const float*)d_in[2],  (const float*)d_in[4],  (const float*)d_in[6],
                           (const float*)d_in[8],  (const float*)d_in[10], (const float*)d_in[12],
                           (const float*)d_in[14], (const float*)d_in[16], (const float*)d_in[18],
                           (const float*)d_in[20], (const float*)d_in[22], (const float*)d_in[24],
                           (const float*)d_in[26]};
    const float* Bs[13] = {(const float*)d_in[3],  (const float*)d_in[5],  (const float*)d_in[7],
                           (const float*)d_in[9],  (const float*)d_in[11], (const float*)d_in[13],
                           (const float*)d_in[15], (const float*)d_in[17], (const float*)d_in[19],
                           (const float*)d_in[21], (const float*)d_in[23], (const float*)d_in[25],
                           (const float*)d_in[27]};
    float* outp = (float*)d_out;

    // ---- workspace layout (bytes) ----
    char* ws = (char*)d_ws;
    f16* IN0 = (f16*)(ws);                       // [8][130][130][224] = 60,569,600 B
    f16* P   = (f16*)(ws + 60569600);            // [8][144][144][128] = 42,467,328 B
    f16* Q   = (f16*)(ws + 103036928);           // [8][160][160][128] = 52,428,800 B
    f16* CC  = (f16*)(ws + 155465728);           // [8][130][130][64]  = 17,305,600 B
    char* WPB = ws + 172771328;
    // PX1/PX2 alias P/Q: consumed by corr BEFORE any conv writes P/Q.
    h2* PX1 = (h2*)P;                            // 33,554,432 B < P
    h2* PX2 = (h2*)Q;                            // 37,879,808 B < Q

    // per-layer: {Co, Ci, CoPad, CiPad}
    const int LC[13][4] = {
        {128, 209, 128, 224}, {128, 128, 128, 128}, {96, 128, 96, 128},
        {64, 96, 64, 96},     {32, 64, 32, 64},     {2, 32, 32, 32},
        {128, 34, 128, 64},   {128, 128, 128, 128}, {128, 128, 128, 128},
        {96, 128, 96, 128},   {64, 96, 64, 96},     {32, 64, 32, 64},
        {2, 32, 32, 32}};
    f16* wpp[13];
    PPA pa;
    {
        size_t off = 0;
        for (int l = 0; l < 13; ++l) {
            wpp[l] = (f16*)(WPB + off);
            off += (size_t)9 * LC[l][2] * LC[l][3] * 2;
            pa.src[l] = W[l]; pa.dst[l] = wpp[l];
            pa.Co[l] = LC[l][0]; pa.Ci[l] = LC[l][1];
            pa.CoPad[l] = LC[l][2]; pa.CiPad[l] = LC[l][3];
        }
    }

    const dim3 blk(256, 1, 1);
    const dim3 blk512(512, 1, 1);

    // weights (single fused launch) + borders of non-aliased buffers
    prepack_all<<<dim3(1008, 1, 13), blk, 0, stream>>>(pa);
    zero_border<<<dim3(67, 1, 8), blk, 0, stream>>>(IN0, 130, 130, 224, 1);
    zero_border<<<dim3(67, 1, 8), blk, 0, stream>>>(CC, 130, 130, 64, 1);

    // pack inputs + correlation
    x1pack<<<dim3(64, 1, 8), blk, 0, stream>>>(x1, IN0, PX1);
    x2pack<<<dim3(73, 64, 8), blk, 0, stream>>>(x2, PX2);
    corr_k<<<dim3(512, 3, 1), blk, 0, stream>>>(PX1, PX2, IN0);

    // PX1/PX2 dead -> restore P/Q borders
    zero_border<<<dim3(81, 1, 8),  blk, 0, stream>>>(P, 144, 144, 128, 8);
    zero_border<<<dim3(100, 1, 8), blk, 0, stream>>>(Q, 160, 160, 128, 16);

    const dim3 cg(512, 1, 1);
    // ---- flow estimator ----
    conv_mfma<1, 4, 0><<<cg, blk512, 0, stream>>>(IN0, 130, 130, 224, 1, wpp[0], Bs[0],
                                                  P, 144, 144, 128, 8, 0, nullptr, 14, 224, 128);
    conv_mfma<1, 4, 0><<<cg, blk512, 0, stream>>>(P, 144, 144, 128, 8, wpp[1], Bs[1],
                                                  Q, 160, 160, 128, 16, 0, nullptr, 8, 128, 128);
    conv_mfma<1, 3, 0><<<cg, blk512, 0, stream>>>(Q, 160, 160, 128, 16, wpp[2], Bs[2],
                                                  P, 144, 144, 128, 8, 0, nullptr, 8, 128, 96);
    conv_mfma<1, 2, 0><<<cg, blk512, 0, stream>>>(P, 144, 144, 128, 8, wpp[3], Bs[3],
                                                  Q, 160, 160, 128, 16, 0, nullptr, 6, 96, 64);
    conv_mfma<1, 1, 0><<<cg, blk512, 0, stream>>>(Q, 160, 160, 128, 16, wpp[4], Bs[4],
                                                  CC, 130, 130, 64, 1, 0, nullptr, 4, 64, 32);
    // flow head: reads CC ch0..31, writes d_out fp32 + CC ch32/33
    conv_mfma<1, 1, 1><<<cg, blk512, 0, stream>>>(CC, 130, 130, 64, 1, wpp[5], Bs[5],
                                                  CC, 130, 130, 64, 1, 32, outp, 2, 32, 32);
    // ---- context network ----
    conv_mfma<1, 4, 0><<<cg, blk512, 0, stream>>>(CC, 130, 130, 64, 1, wpp[6], Bs[6],
                                                  P, 144, 144, 128, 8, 0, nullptr, 4, 64, 128);
    conv_mfma<2, 4, 0><<<cg, blk512, 0, stream>>>(P, 144, 144, 128, 8, wpp[7], Bs[7],
                                                  Q, 160, 160, 128, 16, 0, nullptr, 8, 128, 128);
    conv_mfma<4, 4, 0><<<cg, blk512, 0, stream>>>(Q, 160, 160, 128, 16, wpp[8], Bs[8],
                                                  P, 144, 144, 128, 8, 0, nullptr, 8, 128, 128);
    conv_mfma<8, 3, 0><<<cg, blk512, 0, stream>>>(P, 144, 144, 128, 8, wpp[9], Bs[9],
                                                  Q, 160, 160, 128, 16, 0, nullptr, 8, 128, 96);
    conv_mfma<16, 2, 0><<<cg, blk512, 0, stream>>>(Q, 160, 160, 128, 16, wpp[10], Bs[10],
                                                   P, 144, 144, 128, 8, 0, nullptr, 6, 96, 64);
    conv_mfma<1, 1, 0><<<cg, blk512, 0, stream>>>(P, 144, 144, 128, 8, wpp[11], Bs[11],
                                                  Q, 160, 160, 128, 16, 0, nullptr, 4, 64, 32);
    // final: 32->2, leaky, += flo (d_out)
    conv_mfma<1, 1, 2><<<cg, blk512, 0, stream>>>(Q, 160, 160, 128, 16, wpp[12], Bs[12],
                                                  nullptr, 0, 0, 0, 0, 0, outp, 2, 32, 32);
}

// Round 6
// 778.634 us; speedup vs baseline: 16.2390x; 1.0721x over previous
//
#include <hip/hip_runtime.h>
#include <hip/hip_bf16.h>

typedef _Float16 f16;
typedef __attribute__((ext_vector_type(2)))  _Float16 h2;
typedef __attribute__((ext_vector_type(8)))  _Float16 f16x8;
typedef __attribute__((ext_vector_type(4)))  _Float16 f16x4;
typedef __attribute__((ext_vector_type(16))) float    f32x16;

#define HW16K 16384

__device__ __forceinline__ void gld16(const void* g, void* l) {
    __builtin_amdgcn_global_load_lds((const __attribute__((address_space(1))) void*)g,
                                     (__attribute__((address_space(3))) void*)l, 16, 0, 0);
}

// ---------------------------------------------------------------------------
// Implicit-GEMM 3x3 conv via v_mfma_f32_32x32x16_f16.
// NHWC f16 activations in spatially padded buffers [B][Ye][Xe][Cs].
// Block 512 (8 waves) = 2 output rows x 128 px x (32*PXW*MFW) co channels.
// Wave wv: row t=wv>>2, wq=wv&3 -> pp = wq/(NCO/MFW) px-pair, c = wq%(NCO/MFW)
// co-slot. Wave computes PXW px-tiles x MFW co-tiles (PXW*MFW*16 acc VGPRs).
// gridDim.y = co-groups (Co=128 layers split into 2 groups of 64 -> 4 blk/CU,
// 4x less redundant weight L2 traffic than MF=4 single-group).
// 2-phase pipeline: stage K-tile kt+1 (global_load_lds) before computing kt.
// Weights prepacked [kt][tap][CoPad][16] -> contiguous per-K-tile reads.
// ---------------------------------------------------------------------------
template <int DIL, int PXW, int MFW, int MODE>
__global__ __launch_bounds__(512) void conv_mfma(
    const f16* __restrict__ in, int inYe, int inXe, int inCs, int inPad,
    const f16* __restrict__ wp, const float* __restrict__ bias,
    f16* __restrict__ out, int outYe, int outXe, int outCs, int outPad, int outCoOff,
    float* __restrict__ dout,
    int Ci16, int CiPad, int CoPad)
{
    constexpr int Wext = 128 + 2 * DIL;
    constexpr int NR   = (DIL == 1) ? 4 : 6;
    constexpr int CH   = NR * Wext * 2;        // 16B chunks per K-tile
    constexpr int CHB  = CH * 16;
    constexpr int TI   = (CH + 511) / 512;
    constexpr int NCO  = PXW * MFW;            // co-tiles per block
    constexpr int CPW  = NCO / MFW;            // distinct co-slots per row-group
    __shared__ __align__(16) char smem[2 * CHB];

    const int tid  = threadIdx.x;
    const int lane = tid & 63;
    const int wv   = tid >> 6;
    const int col  = lane & 31;
    const int hi   = lane >> 5;
    const int t    = wv >> 2;          // output row within block
    const int wq   = wv & 3;
    const int pp   = wq / CPW;         // px-pair index
    const int c    = wq % CPW;         // co-slot index
    const int cb0  = blockIdx.y * (32 * NCO);   // co-group base

    const int g  = blockIdx.x;                 // XCD-swizzled (b, ychunk)
    const int n  = (g & 7) * 64 + (g >> 3);
    const int b  = n >> 6;
    const int y0 = (n & 63) * 2;

    const f16* inb = in + (size_t)b * inYe * inXe * inCs;

    auto stage = [&](int kt, int bufi) {
        const int ci0 = kt * 16;
        char* sb = smem + bufi * CHB;
#pragma unroll
        for (int i = 0; i < TI; ++i) {
            int cc = i * 512 + tid;
            if (cc < CH) {
                int r   = cc / (Wext * 2);
                int rem = cc - r * (Wext * 2);
                int px = rem >> 1, half = rem & 1;
                int yin = (DIL == 1) ? (y0 - 1 + r)
                                     : (y0 + (r & 1) + ((r >> 1) - 1) * DIL);
                const f16* src = inb
                    + ((size_t)(yin + inPad) * inXe + (inPad - DIL + px)) * inCs
                    + ci0 + half * 8;
                gld16(src, sb + cc * 16);
            }
        }
    };

    f32x16 acc[PXW][MFW] = {};

    stage(0, 0);
    __syncthreads();
    for (int kt = 0; kt < Ci16; ++kt) {
        if (kt + 1 < Ci16) stage(kt + 1, (kt + 1) & 1);
        const char* sb = smem + (kt & 1) * CHB;
        const f16* wkt = wp + (size_t)kt * 9 * CoPad * 16 + hi * 8;
#pragma unroll
        for (int ky = 0; ky < 3; ++ky) {
#pragma unroll
            for (int kx = 0; kx < 3; ++kx) {
                const int r = (DIL == 1) ? (t + ky) : (ky * 2 + t);
                f16x8 bfr[PXW];
#pragma unroll
                for (int p = 0; p < PXW; ++p)
                    bfr[p] = *(const f16x8*)(sb +
                        ((r * Wext + 32 * (PXW * pp + p) + col + kx * DIL) * 32 + hi * 16));
                const f16* wtap = wkt + (size_t)(ky * 3 + kx) * CoPad * 16;
#pragma unroll
                for (int m = 0; m < MFW; ++m) {
                    const f16x8 afrag =
                        *(const f16x8*)(wtap + (cb0 + 32 * (c * MFW + m) + col) * 16);
#pragma unroll
                    for (int p = 0; p < PXW; ++p)
                        acc[p][m] = __builtin_amdgcn_mfma_f32_32x32x16_f16(
                            afrag, bfr[p], acc[p][m], 0, 0, 0);
                }
            }
        }
        __syncthreads();
    }

    // ---- epilogue ----
    const int y = y0 + t;
    if constexpr (MODE == 0) {
#pragma unroll
        for (int p = 0; p < PXW; ++p) {
            const int x = 32 * (PXW * pp + p) + col;
            const size_t pixbase =
                (((size_t)b * outYe + (y + outPad)) * outXe + (outPad + x)) * outCs + outCoOff;
#pragma unroll
            for (int m = 0; m < MFW; ++m) {
#pragma unroll
                for (int eq = 0; eq < 4; ++eq) {
                    const int co = cb0 + 32 * (c * MFW + m) + 8 * eq + 4 * hi;
                    f16x4 h;
#pragma unroll
                    for (int s = 0; s < 4; ++s) {
                        float v = acc[p][m][4 * eq + s] + bias[co + s];
                        v = (v >= 0.f) ? v : 0.1f * v;
                        h[s] = (f16)v;
                    }
                    *(f16x4*)(out + pixbase + co) = h;
                }
            }
        }
    } else {
        if (hi == 0) {
            const int x = 32 * pp + col;
#pragma unroll
            for (int s = 0; s < 2; ++s) {
                float v = acc[0][0][s] + bias[s];
                const size_t oi = (((size_t)b * 2 + s) * 128 + y) * 128 + x;
                if constexpr (MODE == 1) {
                    dout[oi] = v;
                    const size_t pixbase =
                        (((size_t)b * outYe + (y + outPad)) * outXe + (outPad + x)) * outCs + outCoOff;
                    out[pixbase + s] = (f16)v;
                } else {
                    v = (v >= 0.f) ? v : 0.1f * v;
                    dout[oi] += v;
                }
            }
        }
    }
}

// ---------------------------------------------------------------------------
// Correlation: channel-pair f16 layouts + v_dot2_f32_f16, SCALAR 4B loads.
// dy split over blockIdx.y (3 each).
// PX1: [b][64][128][128][2]   PX2: [b][64][136][136][2] (4-px zero border)
// Writes f16 into IN0 channels 128..208.
// ---------------------------------------------------------------------------
__global__ __launch_bounds__(256) void corr_k(const h2* __restrict__ px1,
                                              const h2* __restrict__ px2,
                                              f16* __restrict__ in0) {
    const int g = blockIdx.x;                  // bijective XCD swizzle
    const int n = (g & 7) * 64 + (g >> 3);
    const int b = n >> 6;
    const int x = threadIdx.x & 127;
    const int y = (n & 63) * 2 + (threadIdx.x >> 7);
    const int dy0 = blockIdx.y * 3;

    const h2* p1  = px1 + (size_t)b * 64 * HW16K + y * 128 + x;
    const h2* p2b = px2 + (size_t)b * 64 * 18496 + (size_t)(y + dy0) * 136 + x;
    f16* orow = in0 + (((size_t)b * 130 + (y + 1)) * 130 + (x + 1)) * 224 + 128;

    float acc[3][9] = {};
    for (int cp = 0; cp < 64; ++cp) {
        const h2 v1 = p1[(size_t)cp * HW16K];
        const h2* rows = p2b + (size_t)cp * 18496;
#pragma unroll
        for (int j = 0; j < 3; ++j) {
            const h2* row = rows + j * 136;
#pragma unroll
            for (int d = 0; d < 9; ++d)
                acc[j][d] = __builtin_amdgcn_fdot2(v1, row[d], acc[j][d], false);
        }
    }
#pragma unroll
    for (int j = 0; j < 3; ++j)
#pragma unroll
        for (int d = 0; d < 9; ++d)
            orow[(dy0 + j) * 9 + d] = (f16)(acc[j][d] * (1.f / 128.f));
}

// x1 fp32 NCHW -> IN0 NHWC ch0..127 AND PX1 channel-pair layout
__global__ __launch_bounds__(256) void x1pack(const float* __restrict__ x1,
                                              f16* __restrict__ in0,
                                              h2* __restrict__ px1) {
    const int x = threadIdx.x & 127;
    const int y = blockIdx.x * 2 + (threadIdx.x >> 7);
    const int b = blockIdx.z;
    const float* p1 = x1 + (size_t)b * 128 * HW16K + y * 128 + x;
    f16* o = in0 + (((size_t)b * 130 + (y + 1)) * 130 + (x + 1)) * 224;
    h2* q = px1 + (size_t)b * 64 * HW16K + y * 128 + x;
    for (int cp = 0; cp < 64; ++cp) {
        const float a0 = p1[(2 * cp) * HW16K];
        const float a1 = p1[(2 * cp + 1) * HW16K];
        h2 v; v[0] = (f16)a0; v[1] = (f16)a1;
        q[(size_t)cp * HW16K] = v;
        *(h2*)(o + 2 * cp) = v;
    }
}

// x2 fp32 NCHW -> PX2 padded channel-pair layout (writes zeros in border)
__global__ __launch_bounds__(256) void x2pack(const float* __restrict__ x2,
                                              h2* __restrict__ px2) {
    const int cell = blockIdx.x * 256 + threadIdx.x;   // over 136x136
    if (cell >= 136 * 136) return;
    const int yp = cell / 136, xp = cell - yp * 136;
    const int cp = blockIdx.y, b = blockIdx.z;
    h2 v; v[0] = (f16)0.f; v[1] = (f16)0.f;
    const int yy = yp - 4, xx = xp - 4;
    if ((unsigned)yy < 128u && (unsigned)xx < 128u) {
        const float* p = x2 + (size_t)b * 128 * HW16K + (2 * cp) * HW16K + yy * 128 + xx;
        v[0] = (f16)p[0];
        v[1] = (f16)p[HW16K];
    }
    px2[((size_t)(b * 64 + cp) * 136 + yp) * 136 + xp] = v;
}

__global__ void zero_border(f16* buf, int Ye, int Xe, int Cs, int pad) {
    const int cell = blockIdx.x * 256 + threadIdx.x;
    const int total = Ye * Xe;
    if (cell >= total) return;
    const int yy = cell / Xe, xx = cell - yy * Xe;
    if (yy >= pad && yy < Ye - pad && xx >= pad && xx < Xe - pad) return;
    f16* p = buf + ((size_t)blockIdx.z * Ye * Xe + cell) * Cs;
    f16x8 z = {};
    for (int c = 0; c < Cs; c += 8) *(f16x8*)(p + c) = z;
}

// all 13 weight tensors: fp32 OIHW -> f16 [kt][tap][CoPad][16], zero-padded
struct PPA {
    const float* src[13];
    f16* dst[13];
    int Co[13], Ci[13], CoPad[13], CiPad[13];
};
__global__ void prepack_all(PPA a) {
    const int l = blockIdx.z;
    const int CoPad = a.CoPad[l], CiPad = a.CiPad[l];
    const int total = 9 * CoPad * CiPad;
    const int i = blockIdx.x * 256 + threadIdx.x;
    if (i >= total) return;
    const int k  = i / (CoPad * CiPad);
    const int r  = i - k * CoPad * CiPad;
    const int co = r / CiPad;
    const int ci = r - co * CiPad;
    f16 v = (f16)0.f;
    if (co < a.Co[l] && ci < a.Ci[l])
        v = (f16)a.src[l][((size_t)co * a.Ci[l] + ci) * 9 + k];
    const int kt = ci >> 4, cin = ci & 15;
    a.dst[l][(((size_t)kt * 9 + k) * CoPad + co) * 16 + cin] = v;
}

extern "C" void kernel_launch(void* const* d_in, const int* in_sizes, int n_in,
                              void* d_out, int out_size, void* d_ws, size_t ws_size,
                              hipStream_t stream) {
    const float* x1 = (const float*)d_in[0];
    const float* x2 = (const float*)d_in[1];
    const float* W[13]  = {(const float*)d_in[2],  (const float*)d_in[4],  (const float*)d_in[6],
                           (const float*)d_in[8],  (const float*)d_in[10], (const float*)d_in[12],
                           (const float*)d_in[14], (const float*)d_in[16], (const float*)d_in[18],
                           (const float*)d_in[20], (const float*)d_in[22], (const float*)d_in[24],
                           (const float*)d_in[26]};
    const float* Bs[13] = {(const float*)d_in[3],  (const float*)d_in[5],  (const float*)d_in[7],
                           (const float*)d_in[9],  (const float*)d_in[11], (const float*)d_in[13],
                           (const float*)d_in[15], (const float*)d_in[17], (const float*)d_in[19],
                           (const float*)d_in[21], (const float*)d_in[23], (const float*)d_in[25],
                           (const float*)d_in[27]};
    float* outp = (float*)d_out;

    // ---- workspace layout (bytes) ----
    char* ws = (char*)d_ws;
    f16* IN0 = (f16*)(ws);                       // [8][130][130][224] = 60,569,600 B
    f16* P   = (f16*)(ws + 60569600);            // [8][144][144][128] = 42,467,328 B
    f16* Q   = (f16*)(ws + 103036928);           // [8][160][160][128] = 52,428,800 B
    f16* CC  = (f16*)(ws + 155465728);           // [8][130][130][64]  = 17,305,600 B
    char* WPB = ws + 172771328;
    // PX1/PX2 alias P/Q: consumed by corr BEFORE any conv writes P/Q.
    h2* PX1 = (h2*)P;                            // 33,554,432 B < P
    h2* PX2 = (h2*)Q;                            // 37,879,808 B < Q

    // per-layer: {Co, Ci, CoPad, CiPad}
    const int LC[13][4] = {
        {128, 209, 128, 224}, {128, 128, 128, 128}, {96, 128, 96, 128},
        {64, 96, 64, 96},     {32, 64, 32, 64},     {2, 32, 32, 32},
        {128, 34, 128, 64},   {128, 128, 128, 128}, {128, 128, 128, 128},
        {96, 128, 96, 128},   {64, 96, 64, 96},     {32, 64, 32, 64},
        {2, 32, 32, 32}};
    f16* wpp[13];
    PPA pa;
    {
        size_t off = 0;
        for (int l = 0; l < 13; ++l) {
            wpp[l] = (f16*)(WPB + off);
            off += (size_t)9 * LC[l][2] * LC[l][3] * 2;
            pa.src[l] = W[l]; pa.dst[l] = wpp[l];
            pa.Co[l] = LC[l][0]; pa.Ci[l] = LC[l][1];
            pa.CoPad[l] = LC[l][2]; pa.CiPad[l] = LC[l][3];
        }
    }

    const dim3 blk(256, 1, 1);
    const dim3 blk512(512, 1, 1);

    // weights (single fused launch) + borders of non-aliased buffers
    prepack_all<<<dim3(1008, 1, 13), blk, 0, stream>>>(pa);
    zero_border<<<dim3(67, 1, 8), blk, 0, stream>>>(IN0, 130, 130, 224, 1);
    zero_border<<<dim3(67, 1, 8), blk, 0, stream>>>(CC, 130, 130, 64, 1);

    // pack inputs + correlation
    x1pack<<<dim3(64, 1, 8), blk, 0, stream>>>(x1, IN0, PX1);
    x2pack<<<dim3(73, 64, 8), blk, 0, stream>>>(x2, PX2);
    corr_k<<<dim3(512, 3, 1), blk, 0, stream>>>(PX1, PX2, IN0);

    // PX1/PX2 dead -> restore P/Q borders
    zero_border<<<dim3(81, 1, 8),  blk, 0, stream>>>(P, 144, 144, 128, 8);
    zero_border<<<dim3(100, 1, 8), blk, 0, stream>>>(Q, 160, 160, 128, 16);

    // ---- flow estimator ----
    conv_mfma<1, 2, 1, 0><<<dim3(512, 2, 1), blk512, 0, stream>>>(IN0, 130, 130, 224, 1, wpp[0], Bs[0],
                                                  P, 144, 144, 128, 8, 0, nullptr, 14, 224, 128);
    conv_mfma<1, 2, 1, 0><<<dim3(512, 2, 1), blk512, 0, stream>>>(P, 144, 144, 128, 8, wpp[1], Bs[1],
                                                  Q, 160, 160, 128, 16, 0, nullptr, 8, 128, 128);
    conv_mfma<1, 1, 3, 0><<<dim3(512, 1, 1), blk512, 0, stream>>>(Q, 160, 160, 128, 16, wpp[2], Bs[2],
                                                  P, 144, 144, 128, 8, 0, nullptr, 8, 128, 96);
    conv_mfma<1, 2, 1, 0><<<dim3(512, 1, 1), blk512, 0, stream>>>(P, 144, 144, 128, 8, wpp[3], Bs[3],
                                                  Q, 160, 160, 128, 16, 0, nullptr, 6, 96, 64);
    conv_mfma<1, 1, 1, 0><<<dim3(512, 1, 1), blk512, 0, stream>>>(Q, 160, 160, 128, 16, wpp[4], Bs[4],
                                                  CC, 130, 130, 64, 1, 0, nullptr, 4, 64, 32);
    // flow head: reads CC ch0..31, writes d_out fp32 + CC ch32/33
    conv_mfma<1, 1, 1, 1><<<dim3(512, 1, 1), blk512, 0, stream>>>(CC, 130, 130, 64, 1, wpp[5], Bs[5],
                                                  CC, 130, 130, 64, 1, 32, outp, 2, 32, 32);
    // ---- context network ----
    conv_mfma<1, 2, 1, 0><<<dim3(512, 2, 1), blk512, 0, stream>>>(CC, 130, 130, 64, 1, wpp[6], Bs[6],
                                                  P, 144, 144, 128, 8, 0, nullptr, 4, 64, 128);
    conv_mfma<2, 2, 1, 0><<<dim3(512, 2, 1), blk512, 0, stream>>>(P, 144, 144, 128, 8, wpp[7], Bs[7],
                                                  Q, 160, 160, 128, 16, 0, nullptr, 8, 128, 128);
    conv_mfma<4, 2, 1, 0><<<dim3(512, 2, 1), blk512, 0, stream>>>(Q, 160, 160, 128, 16, wpp[8], Bs[8],
                                                  P, 144, 144, 128, 8, 0, nullptr, 8, 128, 128);
    conv_mfma<8, 1, 3, 0><<<dim3(512, 1, 1), blk512, 0, stream>>>(P, 144, 144, 128, 8, wpp[9], Bs[9],
                                                  Q, 160, 160, 128, 16, 0, nullptr, 8, 128, 96);
    conv_mfma<16, 2, 1, 0><<<dim3(512, 1, 1), blk512, 0, stream>>>(Q, 160, 160, 128, 16, wpp[10], Bs[10],
                                                   P, 144, 144, 128, 8, 0, nullptr, 6, 96, 64);
    conv_mfma<1, 1, 1, 0><<<dim3(512, 1, 1), blk512, 0, stream>>>(P, 144, 144, 128, 8, wpp[11], Bs[11],
                                                  Q, 160, 160, 128, 16, 0, nullptr, 4, 64, 32);
    // final: 32->2, leaky, += flo (d_out)
    conv_mfma<1, 1, 1, 2><<<dim3(512, 1, 1), blk512, 0, stream>>>(Q, 160, 160, 128, 16, wpp[12], Bs[12],
                                                  nullptr, 0, 0, 0, 0, 0, outp, 2, 32, 32);
}